// Round 6
// baseline (136.180 us; speedup 1.0000x reference)
//
#include <hip/hip_runtime.h>
#include <hip/hip_bf16.h>

// out[b,i] = sum_{j<=i} x[b,j] * kernel[i-j]   (causal Toeplitz matmul)
// M=2048, N=K=4096. f32 in/out, bf16 MFMA compute.
//
// R6: split-K depth 4. 512 threads = 4 K-groups x 2 waves; wave tile 128x64
// (8x4 frags of 16x16x32) cuts LDS fragment reads 25% per FLOP (R5 was
// LDS-port / bubble bound at ~3570 cyc per 128-k step). Iteration = 256-k,
// 2 barriers/iter. Heavy chain 33 -> 17 iters; per-CU iteration totals are
// uniform (~17-18) across all boustrophedon classes. Partials combined via
// 2-stage LDS tree. VGPR ~210 under __launch_bounds__(512,2).

typedef unsigned short u16;
typedef __attribute__((ext_vector_type(8))) short  bf16x8;
typedef __attribute__((ext_vector_type(8))) unsigned short u16x8;
typedef __attribute__((ext_vector_type(4))) float  f32x4;

#define KDIM 4096
#define NDIM 4096
#define MDIM 2048
#define KREV_STRIDE 4608                    // elems per shifted copy
#define KREV_BYTES  (8 * KREV_STRIDE * 2)   // 73728
#define BSTRIDE 520                         // LDS B copy stride (elems)

static __device__ inline u16 f2bf(float f) {
  unsigned u = __builtin_bit_cast(unsigned, f);
  unsigned r = u + 0x7FFFu + ((u >> 16) & 1u);
  return (u16)(r >> 16);
}

static __device__ inline void async_copy16(const void* g, void* l) {
  __builtin_amdgcn_global_load_lds((const __attribute__((address_space(1))) void*)g,
                                   (__attribute__((address_space(3))) void*)l,
                                   16, 0, 0);
}

// Fused prep: blocks [0, conv_blocks) convert x->bf16; last 18 blocks build
// 8 shifted krev copies. krevs[a][u] = krev_logical[u+a-8];
// krev_logical[t] = kern[4095-t] for t in [0,4096) else 0.
__global__ __launch_bounds__(256) void prep(const float* __restrict__ x,
                                            const float* __restrict__ kern,
                                            u16* __restrict__ xb,
                                            u16* __restrict__ krevs,
                                            int conv_blocks) {
  int kb = (int)blockIdx.x - conv_blocks;
  if (kb >= 0) {
    int u = kb * 256 + threadIdx.x;
    for (int a = 0; a < 8; ++a) {
      int t = u + a - 8;
      u16 v = 0;
      if (t >= 0 && t <= 4095) v = f2bf(kern[4095 - t]);
      krevs[a * KREV_STRIDE + u] = v;
    }
  } else {
    size_t i = ((size_t)blockIdx.x * 256 + threadIdx.x) * 8;
    const f32x4* p = (const f32x4*)(x + i);
    f32x4 v0 = p[0], v1 = p[1];
    u16x8 r;
    r[0] = f2bf(v0[0]); r[1] = f2bf(v0[1]); r[2] = f2bf(v0[2]); r[3] = f2bf(v0[3]);
    r[4] = f2bf(v1[0]); r[5] = f2bf(v1[1]); r[6] = f2bf(v1[2]); r[7] = f2bf(v1[3]);
    *(u16x8*)(xb + i) = r;
  }
}

template <bool CONV>
__global__ __launch_bounds__(512, 2) void toeplitz_gemm(const void* __restrict__ Av,
                                                        const u16* __restrict__ krevs,
                                                        float* __restrict__ out) {
  // A: 4 groups x (128 rows x 64 elems) = 65536 B; B: 8*520 elems = 8320 B.
  // Combine overlays: 2 regions x 2 waves x 16 frags x 1088 B = 69632 B.
  __shared__ __align__(16) char smem[73856];
  u16* A_all = (u16*)smem;
  u16* B_all = (u16*)(smem + 65536);

  const int tid  = threadIdx.x;
  const int w    = tid >> 6;        // 0..7
  const int g    = w >> 1;          // K-group 0..3
  const int wn2  = w & 1;           // n-half within group
  const int lane = tid & 63;
  const int lane16 = lane & 15;
  const int quad   = lane >> 4;

  // boustrophedon: class j = b&255 gets ranks {j, 511-j}
  const int b    = (int)blockIdx.x;
  const int rank = (b < 256) ? b : 511 - (b & 255);
  const int ct   = 31 - (rank >> 4);      // column tile, heavy first
  const int n0   = ct * 128;
  const int m0   = (rank & 15) * 128;
  const int W    = 3968 - n0;             // B window base (8-aligned)

  // B frag: elem j of frag(fn) at k = krev_logical[s0 + k], s0 = 4095-n_g+quad*8.
  // LDS holds copies a over window [W + t*256, +512): idx = a*BSTRIDE + (s0&~7)+8-W + (k - t*256).
  int boff[4];
  for (int fn = 0; fn < 4; ++fn) {
    int n_g = n0 + wn2 * 64 + fn * 16 + lane16;
    int s0  = 4095 - n_g + quad * 8;
    int a   = s0 & 7;
    boff[fn] = a * BSTRIDE + (s0 - a + 8 - W);
  }

  f32x4 acc[8][4] = {};

  const int nk    = 2 * ct + 2;           // 64-k slices (covers k < n0+128)
  const int iters = (nk + 3) >> 2;        // 256-k iterations

  const int srow8 = lane >> 3;
  const int ssrc  = ((lane & 7) ^ srow8) * 8;   // XOR source swizzle (16B chunks)

  const u16*  xb = (const u16*)Av;
  const float* xf = (const float*)Av;
  u16* A_g = A_all + g * 8192;

  for (int t = 0; t < iters; ++t) {
    const bool active = (4 * t + g) < nk;
    const int  k0 = t * 256 + g * 64;
    __syncthreads();                      // prior compute's LDS reads done
    // stage B window for this 256-k iteration (single-buffered): 8 waves x 1 copy
    async_copy16(krevs + w * KREV_STRIDE + W + t * 256 + (lane << 3),
                 &B_all[w * BSTRIDE]);
    if (active) {
      if constexpr (CONV) {
        int row = tid & 127;              // thread-in-group
        for (int c = 0; c < 8; ++c) {
          int p = c ^ (row & 7);
          const f32x4* px = (const f32x4*)(xf + (size_t)(m0 + row) * KDIM + k0 + c * 8);
          f32x4 v0 = px[0], v1 = px[1];
          u16x8 r;
          r[0]=f2bf(v0[0]); r[1]=f2bf(v0[1]); r[2]=f2bf(v0[2]); r[3]=f2bf(v0[3]);
          r[4]=f2bf(v1[0]); r[5]=f2bf(v1[1]); r[6]=f2bf(v1[2]); r[7]=f2bf(v1[3]);
          *(u16x8*)(&A_g[row * 64 + p * 8]) = r;
        }
      } else {
        for (int i = 0; i < 8; ++i) {
          int base_row = wn2 * 64 + i * 8;   // + srow8 per lane
          async_copy16(xb + (size_t)(m0 + base_row + srow8) * KDIM + k0 + ssrc,
                       &A_g[base_row * 64]); // wave-uniform; HW adds lane*16B
        }
      }
    }
    __syncthreads();                      // staging drained (vmcnt/lgkm)
    if (active) {
      for (int kk = 0; kk < 2; ++kk) {
        bf16x8 af[8];
        const int p = (kk * 4 + quad) ^ (lane16 & 7);
        for (int fm = 0; fm < 8; ++fm)
          af[fm] = *(const bf16x8*)(&A_g[(fm * 16 + lane16) * 64 + p * 8]);
        bf16x8 bf[4];
        for (int fn = 0; fn < 4; ++fn)
          bf[fn] = *(const bf16x8*)(&B_all[boff[fn] + g * 64 + kk * 32]);
        for (int fm = 0; fm < 8; ++fm)
          for (int fn = 0; fn < 4; ++fn)
            acc[fm][fn] = __builtin_amdgcn_mfma_f32_16x16x32_bf16(af[fm], bf[fn], acc[fm][fn], 0, 0, 0);
      }
    }
  }

  // combine: 2-stage tree. addr = pr*34816 + wn2*17408 + f*1088 + lane*16.
  auto xchg = [&](bool writer, bool reader, int pr) {
    for (int r = 0; r < 2; ++r) {
      __syncthreads();
      if (writer)
        for (int f = 0; f < 16; ++f)
          *(f32x4*)(smem + pr * 34816 + wn2 * 17408 + f * 1088 + lane * 16) =
              acc[r * 4 + (f >> 2)][f & 3];
      __syncthreads();
      if (reader)
        for (int f = 0; f < 16; ++f)
          acc[r * 4 + (f >> 2)][f & 3] +=
              *(const f32x4*)(smem + pr * 34816 + wn2 * 17408 + f * 1088 + lane * 16);
    }
  };
  xchg(g == 1 || g == 3, g == 0 || g == 2, g >> 1);  // g1->g0, g3->g2
  xchg(g == 2, g == 0, 0);                           // g2->g0

  // epilogue (group 0 only): C/D layout col=lane&15, row=quad*4+r
  if (g == 0) {
    for (int fm = 0; fm < 8; ++fm) {
      int row_base = m0 + fm * 16 + quad * 4;
      for (int fn = 0; fn < 4; ++fn) {
        int col = n0 + wn2 * 64 + fn * 16 + lane16;
        for (int r = 0; r < 4; ++r)
          out[(size_t)(row_base + r) * NDIM + col] = acc[fm][fn][r];
      }
    }
  }
}

extern "C" void kernel_launch(void* const* d_in, const int* in_sizes, int n_in,
                              void* d_out, int out_size, void* d_ws, size_t ws_size,
                              hipStream_t stream) {
  const float* x    = (const float*)d_in[0];
  const float* kern = (const float*)d_in[1];
  float* out = (float*)d_out;

  u16* krevs = (u16*)d_ws;
  u16* xb    = (u16*)((char*)d_ws + KREV_BYTES);
  const size_t need_fast = (size_t)KREV_BYTES + (size_t)MDIM * KDIM * 2;

  if (ws_size >= need_fast) {
    prep<<<4096 + 18, 256, 0, stream>>>(x, kern, xb, krevs, 4096);
    toeplitz_gemm<false><<<512, 512, 0, stream>>>(xb, krevs, out);
  } else {
    prep<<<18, 256, 0, stream>>>(x, kern, xb, krevs, 0);
    toeplitz_gemm<true><<<512, 512, 0, stream>>>(x, krevs, out);
  }
}

// Round 7
// 127.937 us; speedup vs baseline: 1.0644x; 1.0644x over previous
//
#include <hip/hip_runtime.h>
#include <hip/hip_bf16.h>

// out[b,i] = sum_{j<=i} x[b,j] * kernel[i-j]   (causal Toeplitz matmul)
// M=2048, N=K=4096. f32 in/out, bf16 MFMA compute.
//
// R7: R5 structure (best: port-saturated while 2 blocks co-reside) + block-level
// split-K. R5's ceiling was the heavy chain (66 slices) running SOLO at 50% port
// util after its light partner retired. Heavy tiles (ct>=16) now split into two
// equal K-halves (<=32 slices each) writing f32 partials to ws; reduce kernel
// sums them. 768 blocks, LPT order, 3 blocks/CU capacity -> co-residency
// persists to the end. Makespan target ~66*870cyc ~ 24-28 us.

typedef unsigned short u16;
typedef __attribute__((ext_vector_type(8))) short  bf16x8;
typedef __attribute__((ext_vector_type(8))) unsigned short u16x8;
typedef __attribute__((ext_vector_type(4))) float  f32x4;

#define KDIM 4096
#define NDIM 4096
#define MDIM 2048
#define KREV_STRIDE 4608                    // elems per shifted copy
#define KREV_BYTES  (8 * KREV_STRIDE * 2)   // 73728
#define BSTRIDE 520                         // LDS B copy stride (elems)
#define XB_BYTES  (MDIM * KDIM * 2)         // 16777216
#define PART_BYTES (2 * 256 * 16384 * 4)    // 33554432 (2 halves x 256 tiles x 64KB)

static __device__ inline u16 f2bf(float f) {
  unsigned u = __builtin_bit_cast(unsigned, f);
  unsigned r = u + 0x7FFFu + ((u >> 16) & 1u);
  return (u16)(r >> 16);
}

static __device__ inline void async_copy16(const void* g, void* l) {
  __builtin_amdgcn_global_load_lds((const __attribute__((address_space(1))) void*)g,
                                   (__attribute__((address_space(3))) void*)l,
                                   16, 0, 0);
}

// Fused prep: blocks [0, conv_blocks) convert x->bf16; last 18 blocks build
// 8 shifted krev copies. krevs[a][u] = krev_logical[u+a-8];
// krev_logical[t] = kern[4095-t] for t in [0,4096) else 0.
__global__ __launch_bounds__(256) void prep(const float* __restrict__ x,
                                            const float* __restrict__ kern,
                                            u16* __restrict__ xb,
                                            u16* __restrict__ krevs,
                                            int conv_blocks) {
  int kb = (int)blockIdx.x - conv_blocks;
  if (kb >= 0) {
    int u = kb * 256 + threadIdx.x;
    for (int a = 0; a < 8; ++a) {
      int t = u + a - 8;
      u16 v = 0;
      if (t >= 0 && t <= 4095) v = f2bf(kern[4095 - t]);
      krevs[a * KREV_STRIDE + u] = v;
    }
  } else {
    size_t i = ((size_t)blockIdx.x * 256 + threadIdx.x) * 8;
    const f32x4* p = (const f32x4*)(x + i);
    f32x4 v0 = p[0], v1 = p[1];
    u16x8 r;
    r[0] = f2bf(v0[0]); r[1] = f2bf(v0[1]); r[2] = f2bf(v0[2]); r[3] = f2bf(v0[3]);
    r[4] = f2bf(v1[0]); r[5] = f2bf(v1[1]); r[6] = f2bf(v1[2]); r[7] = f2bf(v1[3]);
    *(u16x8*)(xb + i) = r;
  }
}

// Sum the two K-half partials of each split tile into out.
// 512 blocks: tileIdx = rb>>1 (ct = 16 + tileIdx>>4, mt = tileIdx&15), rows half rb&1.
__global__ __launch_bounds__(256) void reduce_parts(const float* __restrict__ partials,
                                                    float* __restrict__ out) {
  const int rb = (int)blockIdx.x;
  const int tileIdx = rb >> 1;
  const int hh = rb & 1;
  const int ct = 16 + (tileIdx >> 4);
  const int mt = tileIdx & 15;
  const f32x4* p0 = (const f32x4*)(partials + (size_t)tileIdx * 16384);
  const f32x4* p1 = (const f32x4*)(partials + (size_t)(256 + tileIdx) * 16384);
  for (int i = 0; i < 8; ++i) {
    int chunk = hh * 2048 + (int)threadIdx.x + i * 256;   // f32x4 index in tile
    int row = chunk >> 5;
    int c4  = chunk & 31;
    f32x4 v = p0[chunk];
    f32x4 w = p1[chunk];
    v[0]+=w[0]; v[1]+=w[1]; v[2]+=w[2]; v[3]+=w[3];
    *(f32x4*)(out + (size_t)(mt * 128 + row) * NDIM + ct * 128 + c4 * 4) = v;
  }
}

template <bool CONV>
__global__ __launch_bounds__(512, 4) void toeplitz_gemm(const void* __restrict__ Av,
                                                        const u16* __restrict__ krevs,
                                                        float* __restrict__ out,
                                                        float* __restrict__ partials,
                                                        int split_mode) {
  __shared__ __align__(16) char smem_raw[49408];
  u16*   A_all = (u16*)smem_raw;              // 2 groups x 8192 elems (single-buffered per group)
  u16*   B_all = (u16*)(smem_raw + 32768);    // 2 bufs x 4160 elems
  f32x4* ep    = (f32x4*)smem_raw;            // combine overlay

  const int tid  = threadIdx.x;
  const int w    = tid >> 6;        // 0..7
  const int g    = w >> 2;          // K-group 0..1
  const int wl   = w & 3;           // wave-in-group
  const int lane = tid & 63;
  const int lane16 = lane & 15;
  const int quad   = lane >> 4;
  const int wm = wl >> 1;
  const int wn = wl & 1;

  // ---- block -> work mapping ----
  int ct, mt, s0, cnt, h = 0, split = 0;
  const int b = (int)blockIdx.x;
  if (split_mode) {
    // LPT order: groups by slice-count desc. pairs of cnt levels (even,odd) = 80 ids.
    if (b < 640) {
      int p = b / 80, r = b % 80;
      if (r < 48) {
        if (r < 32) { split = 1; ct = 31 - 2 * p; h = r >> 4; mt = r & 15; }
        else        { split = 0; ct = 15 - p;     mt = r - 32; }
      } else        { split = 1; ct = 30 - 2 * p; int r2 = r - 48; h = r2 >> 4; mt = r2 & 15; }
    } else {
      int j = b - 640; split = 0; ct = 7 - (j >> 4); mt = j & 15;
    }
  } else {
    const int rank = (b < 256) ? b : 511 - (b & 255);
    ct = 31 - (rank >> 4); mt = rank & 15;
  }
  if (split) { s0 = h * (ct + 1); cnt = ct + 1; }
  else       { s0 = 0;            cnt = 2 * ct + 2; }

  const int n0 = ct * 128;
  const int m0 = mt * 128;
  const int W  = 3968 - n0;               // B window base (8-aligned)

  // B frag offsets (W-based; the s0*64 window shift cancels in the index algebra)
  int boff[4];
  for (int fn = 0; fn < 4; ++fn) {
    int n_g = n0 + wn * 64 + fn * 16 + lane16;
    int s0f = 4095 - n_g + quad * 8;
    int a   = s0f & 7;
    boff[fn] = a * BSTRIDE + (s0f - a + 8 - W);
  }

  f32x4 acc[4][4] = {};
  const int srow8 = lane >> 3;
  const int ssrc  = ((lane & 7) ^ srow8) * 8;   // XOR source swizzle (16B chunks)

  const u16*  xb = (const u16*)Av;
  const float* xf = (const float*)Av;
  u16* A_g = A_all + g * 8192;

  auto stageA = [&](int ls) {              // ls = local slice index (this group's)
    const int k0 = (s0 + ls) * 64;
    if constexpr (CONV) {
      int j    = tid & 255;
      int row  = j >> 1;
      int lh   = j & 1;
      for (int lc = 0; lc < 4; ++lc) {
        int l = lh * 4 + lc;
        int p = l ^ (row & 7);
        const f32x4* px = (const f32x4*)(xf + (size_t)(m0 + row) * KDIM + k0 + l * 8);
        f32x4 v0 = px[0], v1 = px[1];
        u16x8 r;
        r[0]=f2bf(v0[0]); r[1]=f2bf(v0[1]); r[2]=f2bf(v0[2]); r[3]=f2bf(v0[3]);
        r[4]=f2bf(v1[0]); r[5]=f2bf(v1[1]); r[6]=f2bf(v1[2]); r[7]=f2bf(v1[3]);
        *(u16x8*)(&A_g[row * 64 + p * 8]) = r;
      }
    } else {
      for (int c = 0; c < 4; ++c) {
        int g8  = c * 4 + wl;
        int row = g8 * 8 + srow8;
        async_copy16(xb + (size_t)(m0 + row) * KDIM + k0 + ssrc,
                     &A_g[g8 * 512]);
      }
    }
  };
  auto stageB = [&](int c) {
    async_copy16(krevs + w * KREV_STRIDE + W + s0 * 64 + c * 256 + (lane << 3),
                 &B_all[(c & 1) * 4160 + w * BSTRIDE]);
  };

  const int T   = (cnt + 1) >> 1;          // iterations (128-k pairs)
  const int nch = (T + 1) >> 1;            // B chunks (256-k)

  // prologue
  stageB(0);
  stageA(g);                                // slice 2*0+g (cnt>=2 -> both active)

  for (int t = 0;; ++t) {
    __syncthreads();                       // stage(t) drained
    if (2 * t + g < cnt) {
      const u16* Bb  = B_all + ((t >> 1) & 1) * 4160;
      const int  ksl = (t & 1) * 128 + g * 64;
      for (int kk = 0; kk < 2; ++kk) {
        bf16x8 af[4];
        const int p = (kk * 4 + quad) ^ (lane16 & 7);
        for (int fm = 0; fm < 4; ++fm) {
          int row = wm * 64 + fm * 16 + lane16;
          af[fm] = *(const bf16x8*)(&A_g[row * 64 + p * 8]);
        }
        bf16x8 bf[4];
        for (int fn = 0; fn < 4; ++fn)
          bf[fn] = *(const bf16x8*)(&Bb[boff[fn] + ksl + kk * 32]);
        for (int fm = 0; fm < 4; ++fm)
          for (int fn = 0; fn < 4; ++fn)
            acc[fm][fn] = __builtin_amdgcn_mfma_f32_16x16x32_bf16(af[fm], bf[fn], acc[fm][fn], 0, 0, 0);
      }
    }
    if (t + 1 == T) break;
    __syncthreads();                       // reads of step t complete
    if (2 * (t + 1) + g < cnt) stageA(2 * (t + 1) + g);
    if (!(t & 1) && (t >> 1) + 1 < nch) stageB((t >> 1) + 1);
  }

  // combine: group1 partials -> group0 via LDS (2 rounds)
  const int j = tid & 255;
  for (int r = 0; r < 2; ++r) {
    __syncthreads();
    if (g == 1) {
      for (int fm2 = 0; fm2 < 2; ++fm2)
        for (int fn = 0; fn < 4; ++fn)
          ep[j * 9 + fm2 * 4 + fn] = acc[r * 2 + fm2][fn];
    }
    __syncthreads();
    if (g == 0) {
      for (int fm2 = 0; fm2 < 2; ++fm2)
        for (int fn = 0; fn < 4; ++fn)
          acc[r * 2 + fm2][fn] += ep[j * 9 + fm2 * 4 + fn];
    }
  }

  // epilogue (group 0): C/D layout col=lane&15, row=quad*4+r
  if (g == 0) {
    if (split) {
      float* pp = partials + (size_t)(h * 256 + (ct - 16) * 16 + mt) * 16384;
      for (int fm = 0; fm < 4; ++fm) {
        int rl = wm * 64 + fm * 16 + quad * 4;
        for (int fn = 0; fn < 4; ++fn) {
          int cl = wn * 64 + fn * 16 + lane16;
          for (int r = 0; r < 4; ++r)
            pp[(rl + r) * 128 + cl] = acc[fm][fn][r];
        }
      }
    } else {
      for (int fm = 0; fm < 4; ++fm) {
        int row_base = m0 + wm * 64 + fm * 16 + quad * 4;
        for (int fn = 0; fn < 4; ++fn) {
          int col = n0 + wn * 64 + fn * 16 + lane16;
          for (int r = 0; r < 4; ++r)
            out[(size_t)(row_base + r) * NDIM + col] = acc[fm][fn][r];
        }
      }
    }
  }
}

extern "C" void kernel_launch(void* const* d_in, const int* in_sizes, int n_in,
                              void* d_out, int out_size, void* d_ws, size_t ws_size,
                              hipStream_t stream) {
  const float* x    = (const float*)d_in[0];
  const float* kern = (const float*)d_in[1];
  float* out = (float*)d_out;

  u16*   krevs    = (u16*)d_ws;
  u16*   xb       = (u16*)((char*)d_ws + KREV_BYTES);
  float* partials = (float*)((char*)d_ws + KREV_BYTES + XB_BYTES);

  const size_t need_fast  = (size_t)KREV_BYTES + XB_BYTES;
  const size_t need_split = need_fast + PART_BYTES;

  if (ws_size >= need_split) {
    prep<<<4096 + 18, 256, 0, stream>>>(x, kern, xb, krevs, 4096);
    toeplitz_gemm<false><<<768, 512, 0, stream>>>(xb, krevs, out, partials, 1);
    reduce_parts<<<512, 256, 0, stream>>>(partials, out);
  } else if (ws_size >= need_fast) {
    prep<<<4096 + 18, 256, 0, stream>>>(x, kern, xb, krevs, 4096);
    toeplitz_gemm<false><<<512, 512, 0, stream>>>(xb, krevs, out, partials, 0);
  } else {
    prep<<<18, 256, 0, stream>>>(x, kern, xb, krevs, 0);
    toeplitz_gemm<true><<<512, 512, 0, stream>>>(x, krevs, out, partials, 0);
  }
}